// Round 5
// baseline (280.402 us; speedup 1.0000x reference)
//
#include <hip/hip_runtime.h>
#include <hip/hip_fp16.h>
#include <math.h>

#define NATOM 8192  // NB * NLOC

namespace {

typedef _Float16 half8 __attribute__((ext_vector_type(8)));
typedef _Float16 half2t __attribute__((ext_vector_type(2)));
typedef float f32x4 __attribute__((ext_vector_type(4)));

// ws layout (halfs): [0,32768) wkvp | [32768,49152) Wqp_t | [49152,65536) Whp_t
// wkvp: 32 MFMA A-tiles of 16 kv-columns each.
//   Tiles 0..15  = K columns (orig Wkv col c = d*8 + h)
//   Tiles 16..31 = V columns (orig Wkv col c = d*8 + 4 + h)
//   Tile T, row m (0..15): d = (T&15)*4 + (m>>2), h = m&3
//   A-frag element: lane l = lqk*16 + m holds features i = ks*32 + lqk*8 + jj
__global__ void pack_weights(const float* __restrict__ Wkv,
                             const float* __restrict__ Wq,
                             const float* __restrict__ Wh,
                             _Float16* __restrict__ out) {
  int tid = blockIdx.x * 256 + threadIdx.x;  // 0..65535
  if (tid < 32768) {
    // (i,c) with c fastest -> coalesced read of Wkv[i][c]
    int i = tid >> 9, c = tid & 511;
    int ks = i >> 5, jj = i & 7, lqk = (i >> 3) & 3;
    int d = c >> 3, e = c & 7, isv = e >> 2, h = e & 3;
    int T = isv * 16 + (d >> 2);
    int m = ((d & 3) << 2) | h;
    int l = lqk * 16 + m;
    out[(((T * 2 + ks) * 64) + l) * 8 + jj] = (_Float16)Wkv[i * 512 + c];
  } else if (tid < 49152) {
    int idx = tid - 32768;          // Wq is [i][c], 64x256
    int i = idx >> 8, c = idx & 255;
    out[32768 + c * 64 + i] = (_Float16)Wq[i * 256 + c];   // Wqp_t[c][i]
  } else {
    int idx = tid - 49152;          // Wh is [k][c], 256x64
    int k = idx >> 6, c = idx & 63;
    out[49152 + c * 256 + k] = (_Float16)Wh[k * 64 + c];   // Whp_t[c][k]
  }
}

__device__ __forceinline__ float dot8(half8 a, half8 b, float acc) {
  acc = __builtin_amdgcn_fdot2((half2t){a[0], a[1]}, (half2t){b[0], b[1]}, acc, false);
  acc = __builtin_amdgcn_fdot2((half2t){a[2], a[3]}, (half2t){b[2], b[3]}, acc, false);
  acc = __builtin_amdgcn_fdot2((half2t){a[4], a[5]}, (half2t){b[4], b[5]}, acc, false);
  acc = __builtin_amdgcn_fdot2((half2t){a[6], a[7]}, (half2t){b[6], b[7]}, acc, false);
  return acc;
}

// ONE WAVE = ONE ATOM. Zero __syncthreads: the 4 waves of a block process 4
// independent atoms with wave-private LDS slices; all LDS RAW deps are
// wave-internal and ordered by compiler-inserted lgkmcnt. This removes the
// 6-barrier convoy AND the vmcnt(0)-drain-at-barrier that serialized staging.
// launch_bounds(256,2): VGPR cap 128 — allocator has room, no spills (rounds
// 2-4 proved forced caps spill and spills cost more than occupancy gains).
__global__ __launch_bounds__(256, 2)
void local_atten_kernel(const float* __restrict__ g1,
                        const float* __restrict__ gg1,
                        const int* __restrict__ mask,
                        const _Float16* __restrict__ wpack,
                        const float* __restrict__ bh,
                        float* __restrict__ out) {
  // LDS per wave: gs 8192 + qs 1024 + rets 512 + g1s 128 = 9856 B; x4 = 39424 B
  __shared__ __align__(16) __half gs[4][4096];   // gg1 tile, fp16, swizzled
  __shared__ __align__(16) float  qs[4][256];    // q flat col = d*4 + h
  __shared__ __align__(16) __half rets[4][256];  // o flat k = h*64 + d
  __shared__ __align__(16) __half g1s[4][64];

  const _Float16* wkvp = wpack;
  const _Float16* wqp  = wpack + 32768;
  const _Float16* whp  = wpack + 49152;

  const int t = threadIdx.x;
  const int lane = t & 63;
  const int wave = t >> 6;
  const int lq = lane >> 4;   // quad within wave
  const int lr = lane & 15;
  const int atom = blockIdx.x * 4 + wave;

  __half* gsw  = gs[wave];
  float*  qsw  = qs[wave];
  __half* retw = rets[wave];
  __half* g1w  = g1s[wave];

  // ---- early independent loads: mask (per-lane j = jt*16+lr), first A-tile ----
  int mreg[4];
#pragma unroll
  for (int jt = 0; jt < 4; ++jt)
    mreg[jt] = mask[(size_t)atom * 64 + jt * 16 + lr];

  const half8* ap_base = reinterpret_cast<const half8*>(wkvp);
  half8 a0 = ap_base[lane];        // tile 0, ks=0
  half8 a1 = ap_base[64 + lane];   // tile 0, ks=1

  g1w[lane] = __float2half(g1[(size_t)atom * 64 + lane]);

  // ---- stage own gg1 tile (64 nei x 64 feat) as fp16, swizzled for b128 ----
  // logical gs[j][i]; physical half offset = j*64 + ((g ^ (j&7))<<3) + (i&7)
  // Two explicit batches of 8 loads: deep vmcnt pipeline, bounded transient regs.
  {
    const float4* src = reinterpret_cast<const float4*>(gg1 + (size_t)atom * 4096);
#pragma unroll
    for (int bat = 0; bat < 2; ++bat) {
      float4 v[8];
#pragma unroll
      for (int r = 0; r < 8; ++r) v[r] = src[lane + 64 * (bat * 8 + r)];
#pragma unroll
      for (int r = 0; r < 8; ++r) {
        int idx4 = lane + 64 * (bat * 8 + r);
        int j = idx4 >> 4;
        int i4 = (idx4 & 15) << 2;
        __half2 h01 = __floats2half2_rn(v[r].x, v[r].y);
        __half2 h23 = __floats2half2_rn(v[r].z, v[r].w);
        int g = i4 >> 3;
        int addr = j * 64 + ((g ^ (j & 7)) << 3) + (i4 & 7);
        union { __half2 h[2]; uint2 u; } pk;
        pk.h[0] = h01; pk.h[1] = h23;
        *reinterpret_cast<uint2*>(&gsw[addr]) = pk.u;
      }
    }
  }

  // ---- q for ALL 256 flat cols, 4 per lane (c = lane*4+cc = d*4+h) ----
  // Needs only g1w (wave-internal lgkmcnt); staging loads still in flight here.
  {
    const half8* grow = reinterpret_cast<const half8*>(g1w);
    float4 qv;
#pragma unroll
    for (int cc = 0; cc < 4; ++cc) {
      const half8* wrow = reinterpret_cast<const half8*>(wqp + (lane * 4 + cc) * 64);
      float qacc = 0.f;
#pragma unroll
      for (int ks = 0; ks < 8; ++ks) qacc = dot8(wrow[ks], grow[ks], qacc);
      qv[cc] = qacc;
    }
    *reinterpret_cast<float4*>(&qsw[lane * 4]) = qv;
  }

  // ---- B-fragments: all 4 j-tiles x 2 k-steps pinned (8 ds_read_b128) ----
  half8 bfrag[4][2];
  {
    const __half* bp0 = &gsw[lr * 64 + ((lq ^ (lr & 7)) << 3)];
    const __half* bp1 = &gsw[lr * 64 + (((4 + lq) ^ (lr & 7)) << 3)];
#pragma unroll
    for (int jt = 0; jt < 4; ++jt) {
      bfrag[jt][0] = *reinterpret_cast<const half8*>(bp0 + jt * 1024);
      bfrag[jt][1] = *reinterpret_cast<const half8*>(bp1 + jt * 1024);
    }
  }

  // ---- K-phase: all 16 K-tiles. Lane holds K[d=T*4+lq][h=r][j=jt*16+lr];
  // fold q[d][h] in immediately; sacc[jt][h] accumulates over this lane's d. ----
  float sacc[4][4];
#pragma unroll
  for (int jt = 0; jt < 4; ++jt)
#pragma unroll
    for (int h = 0; h < 4; ++h) sacc[jt][h] = 0.f;

#pragma unroll
  for (int T = 0; T < 16; ++T) {
    // depth-1 prefetch; T=15 naturally prefetches tile 16 = first V-tile
    half8 na0 = ap_base[(T + 1) * 128 + lane];
    half8 na1 = ap_base[(T + 1) * 128 + 64 + lane];
    const int d = T * 4 + lq;
    float4 q4 = *reinterpret_cast<const float4*>(&qsw[d * 4]);  // quad broadcast
#pragma unroll
    for (int jt = 0; jt < 4; ++jt) {
      f32x4 acc = {0.f, 0.f, 0.f, 0.f};
      acc = __builtin_amdgcn_mfma_f32_16x16x32_f16(a0, bfrag[jt][0], acc, 0, 0, 0);
      acc = __builtin_amdgcn_mfma_f32_16x16x32_f16(a1, bfrag[jt][1], acc, 0, 0, 0);
      sacc[jt][0] = fmaf(acc[0], q4.x, sacc[jt][0]);
      sacc[jt][1] = fmaf(acc[1], q4.y, sacc[jt][1]);
      sacc[jt][2] = fmaf(acc[2], q4.z, sacc[jt][2]);
      sacc[jt][3] = fmaf(acc[3], q4.w, sacc[jt][3]);
    }
    a0 = na0; a1 = na1;
  }

  // butterfly over lq: every lane gets the complete s[jt][h] for its (jt,lr) js
#pragma unroll
  for (int jt = 0; jt < 4; ++jt)
#pragma unroll
    for (int h = 0; h < 4; ++h) {
      sacc[jt][h] += __shfl_xor(sacc[jt][h], 16);
      sacc[jt][h] += __shfl_xor(sacc[jt][h], 32);
    }

  // ---- in-register masked softmax per head (reduce over lr within 16-group;
  // lanes differing only in lq hold identical values, so 4 shfl steps suffice) ----
  float aw[4][4];  // [jt][h]
  {
#pragma unroll
    for (int jt = 0; jt < 4; ++jt)
#pragma unroll
      for (int h = 0; h < 4; ++h)
        sacc[jt][h] = mreg[jt] ? sacc[jt][h] * 0.125f : -INFINITY;
#pragma unroll
    for (int h = 0; h < 4; ++h) {
      float mx = fmaxf(fmaxf(sacc[0][h], sacc[1][h]), fmaxf(sacc[2][h], sacc[3][h]));
#pragma unroll
      for (int off = 8; off > 0; off >>= 1) mx = fmaxf(mx, __shfl_xor(mx, off));
      float p0 = mreg[0] ? __expf(sacc[0][h] - mx) : 0.f;
      float p1 = mreg[1] ? __expf(sacc[1][h] - mx) : 0.f;
      float p2 = mreg[2] ? __expf(sacc[2][h] - mx) : 0.f;
      float p3 = mreg[3] ? __expf(sacc[3][h] - mx) : 0.f;
      float sum = p0 + p1 + p2 + p3;
#pragma unroll
      for (int off = 8; off > 0; off >>= 1) sum += __shfl_xor(sum, off);
      float inv = (sum > 0.f) ? (1.f / sum) : 0.f;
      aw[0][h] = p0 * inv; aw[1][h] = p1 * inv;
      aw[2][h] = p2 * inv; aw[3][h] = p3 * inv;
    }
  }

  // ---- V-phase: all 16 V-tiles; PV contraction straight out of accumulators;
  // j-sum by 16-lane butterfly; o goes to wave-private rets (no cross-wave). ----
#pragma unroll
  for (int Ti = 0; Ti < 16; ++Ti) {
    const int T = 16 + Ti;
    half8 na0 = a0, na1 = a1;
    if (Ti < 15) {
      na0 = ap_base[(T + 1) * 128 + lane];
      na1 = ap_base[(T + 1) * 128 + 64 + lane];
    }
    float part[4] = {0.f, 0.f, 0.f, 0.f};
#pragma unroll
    for (int jt = 0; jt < 4; ++jt) {
      f32x4 acc = {0.f, 0.f, 0.f, 0.f};
      acc = __builtin_amdgcn_mfma_f32_16x16x32_f16(a0, bfrag[jt][0], acc, 0, 0, 0);
      acc = __builtin_amdgcn_mfma_f32_16x16x32_f16(a1, bfrag[jt][1], acc, 0, 0, 0);
      part[0] = fmaf(acc[0], aw[jt][0], part[0]);
      part[1] = fmaf(acc[1], aw[jt][1], part[1]);
      part[2] = fmaf(acc[2], aw[jt][2], part[2]);
      part[3] = fmaf(acc[3], aw[jt][3], part[3]);
    }
#pragma unroll
    for (int r = 0; r < 4; ++r) {
      part[r] += __shfl_xor(part[r], 1);
      part[r] += __shfl_xor(part[r], 2);
      part[r] += __shfl_xor(part[r], 4);
      part[r] += __shfl_xor(part[r], 8);
    }
    if (lr == 0) {
      const int d = Ti * 4 + lq;
#pragma unroll
      for (int r = 0; r < 4; ++r) retw[r * 64 + d] = __float2half(part[r]);
    }
    a0 = na0; a1 = na1;
  }

  // ---- out col c = lane: full k=0..255 dot (2 chains for ILP) + bias ----
  {
    const half8* wrow = reinterpret_cast<const half8*>(whp + lane * 256);
    const half8* rrow = reinterpret_cast<const half8*>(retw);  // LDS broadcast
    float o0 = 0.f, o1 = 0.f;
#pragma unroll
    for (int ks = 0; ks < 16; ++ks) {
      o0 = dot8(wrow[ks], rrow[ks], o0);
      o1 = dot8(wrow[16 + ks], rrow[16 + ks], o1);
    }
    out[(size_t)atom * 64 + lane] = o0 + o1 + bh[lane];
  }
}

}  // namespace

extern "C" void kernel_launch(void* const* d_in, const int* in_sizes, int n_in,
                              void* d_out, int out_size, void* d_ws, size_t ws_size,
                              hipStream_t stream) {
  const float* g1   = (const float*)d_in[0];
  const float* gg1  = (const float*)d_in[1];
  const int*   mask = (const int*)d_in[2];
  const float* Wq   = (const float*)d_in[3];
  const float* Wkv  = (const float*)d_in[4];
  const float* Wh   = (const float*)d_in[5];
  const float* bh   = (const float*)d_in[6];
  float* out = (float*)d_out;
  (void)in_sizes; (void)n_in; (void)ws_size; (void)out_size;

  _Float16* wpack = (_Float16*)d_ws;   // 65536 halfs = 128 KB
  pack_weights<<<256, 256, 0, stream>>>(Wkv, Wq, Wh, wpack);
  local_atten_kernel<<<NATOM / 4, 256, 0, stream>>>(g1, gg1, mask, wpack, bh, out);
}

// Round 8
// 272.093 us; speedup vs baseline: 1.0305x; 1.0305x over previous
//
#include <hip/hip_runtime.h>
#include <hip/hip_fp16.h>
#include <math.h>

#define NATOM 8192  // NB * NLOC

namespace {

typedef _Float16 half8 __attribute__((ext_vector_type(8)));
typedef _Float16 half2t __attribute__((ext_vector_type(2)));
typedef float f32x4 __attribute__((ext_vector_type(4)));

// Wave-internal LDS RAW fence: orders prior ds_writes against later ds_reads
// at both compiler level ("memory" clobber + sched_barrier) and HW level
// (lgkmcnt(0)). Does NOT touch vmcnt -> global prefetches stay in flight.
#define LDS_FENCE()                                        \
  do {                                                     \
    asm volatile("s_waitcnt lgkmcnt(0)" ::: "memory");     \
    __builtin_amdgcn_sched_barrier(0);                     \
  } while (0)

// ---- weight folding (the 33x FLOP cut) ----------------------------------
// ws layout (halfs): [0,16384) M_t | [16384,32768) Wvh_t
//   M_t[(h*64+i)][i'] = sum_d Wq[i'][d*4+h]   * Wkv[i][d*8+h]     (K fold)
//   Wvh_t[c][h*64+i]  = sum_d Wkv[i][d*8+4+h] * Wh[(h*64+d)][c]   (V@Wh fold)
// Computed in fp32, rounded to fp16 once. Wq/Wkv/Wh are never read at runtime.
__global__ void pack_weights(const float* __restrict__ Wq,
                             const float* __restrict__ Wkv,
                             const float* __restrict__ Wh,
                             _Float16* __restrict__ out) {
  int tid = blockIdx.x * 256 + threadIdx.x;   // 0..32767
  if (tid < 16384) {
    int r = tid >> 6, ip = tid & 63;          // r = h*64+i
    int h = r >> 6, i = r & 63;
    float acc = 0.f;
#pragma unroll 8
    for (int d = 0; d < 64; ++d)
      acc += Wq[ip * 256 + d * 4 + h] * Wkv[i * 512 + d * 8 + h];
    out[tid] = (_Float16)acc;
  } else {
    int idx = tid - 16384;
    int c = idx >> 8, k2 = idx & 255;         // k2 = h*64+i
    int h = k2 >> 6, i = k2 & 63;
    float acc = 0.f;
#pragma unroll 8
    for (int d = 0; d < 64; ++d)
      acc += Wkv[i * 512 + d * 8 + 4 + h] * Wh[(h * 64 + d) * 64 + c];
    out[16384 + idx] = (_Float16)acc;
  }
}

__device__ __forceinline__ float dot8(half8 a, half8 b, float acc) {
  acc = __builtin_amdgcn_fdot2((half2t){a[0], a[1]}, (half2t){b[0], b[1]}, acc, false);
  acc = __builtin_amdgcn_fdot2((half2t){a[2], a[3]}, (half2t){b[2], b[3]}, acc, false);
  acc = __builtin_amdgcn_fdot2((half2t){a[4], a[5]}, (half2t){b[4], b[5]}, acc, false);
  acc = __builtin_amdgcn_fdot2((half2t){a[6], a[7]}, (half2t){b[6], b[7]}, acc, false);
  return acc;
}

__device__ __forceinline__ half8 cvt8(float4 a, float4 b) {
  half8 r;
  r[0] = (_Float16)a.x; r[1] = (_Float16)a.y; r[2] = (_Float16)a.z; r[3] = (_Float16)a.w;
  r[4] = (_Float16)b.x; r[5] = (_Float16)b.y; r[6] = (_Float16)b.z; r[7] = (_Float16)b.w;
  return r;
}

// ONE WAVE = ONE ATOM, zero barriers, 16 MFMAs/atom total.
// LDS per wave (_Float16): rows 0..15 stride 72 (A-frag scratch; pad kills the
// stride-64 bank conflict), g1h[64] @1152, us[256] @1216. 1536 halfs = 3 KB.
// Rows 0-3 hold qk~ (s-phase A), then aw (u-phase A); rows 4-15 zeroed.
// All four LDS RAW handoffs are protected by LDS_FENCE() — round-6 failed
// because the aw->Au handoff was reordered (absmax 37.7 == stale-qk~ signature).
__global__ __launch_bounds__(256, 4)
void local_atten_kernel(const float* __restrict__ g1,
                        const float* __restrict__ gg1,
                        const int* __restrict__ mask,
                        const _Float16* __restrict__ wpack,
                        const float* __restrict__ bh,
                        float* __restrict__ out) {
  __shared__ __align__(16) _Float16 qa[4][1536];   // 12288 B / block

  const _Float16* Mt  = wpack;            // 16384 halfs
  const _Float16* Wvh = wpack + 16384;    // 16384 halfs

  const int t = threadIdx.x;
  const int lane = t & 63;
  const int wave = t >> 6;
  const int lq = lane >> 4;
  const int lr = lane & 15;
  const int atom = blockIdx.x * 4 + wave;

  _Float16* qaw = qa[wave];
  const float* gbase = gg1 + (size_t)atom * 4096;

  // ---- early independent loads ----
  int mreg[4];
#pragma unroll
  for (int jt = 0; jt < 4; ++jt)
    mreg[jt] = mask[(size_t)atom * 64 + jt * 16 + lr];

  qaw[1152 + lane] = (_Float16)g1[(size_t)atom * 64 + lane];

  // zero unused A-scratch rows 4..15 (cols 0..63): MFMA rows 4..15 read these
#pragma unroll
  for (int r = 4; r < 16; ++r) qaw[r * 72 + lane] = (_Float16)0.f;

  // first s-tile rows (jt=0) prefetch: row j=lr, i-chunks lq*8 and 32+lq*8
  float4 cur[4];
  {
    const float4* p = reinterpret_cast<const float4*>(gbase + lr * 64 + lq * 8);
    cur[0] = p[0]; cur[1] = p[1]; cur[2] = p[8]; cur[3] = p[9];   // +32 floats
  }

  LDS_FENCE();   // g1h (and zeros) visible before the qk~ dot reads them

  // ---- qk~[i=lane][h] = g1 . M_t[h*64+lane] (fp16 dot2, fp32 acc) ----
  {
    const half8* grow = reinterpret_cast<const half8*>(qaw + 1152);
    half8 gr[8];
#pragma unroll
    for (int ks = 0; ks < 8; ++ks) gr[ks] = grow[ks];
#pragma unroll
    for (int h = 0; h < 4; ++h) {
      const half8* mrow = reinterpret_cast<const half8*>(Mt + (h * 64 + lane) * 64);
      float a = 0.f;
#pragma unroll
      for (int ks = 0; ks < 8; ++ks) a = dot8(mrow[ks], gr[ks], a);
      qaw[h * 72 + lane] = (_Float16)a;
    }
  }

  LDS_FENCE();   // qk~ rows 0..3 visible before A-frag b128 reads

  // ---- s-phase: A = qk~ (m=h, k=i), B = gg1 rows from global (k=i, n=j) ----
  half8 A0 = *reinterpret_cast<const half8*>(qaw + lr * 72 + lq * 8);
  half8 A1 = *reinterpret_cast<const half8*>(qaw + lr * 72 + 32 + lq * 8);

  f32x4 sa[4];
#pragma unroll
  for (int jt = 0; jt < 4; ++jt) {
    float4 nxt[4];
    if (jt < 3) {
      const float4* p =
          reinterpret_cast<const float4*>(gbase + ((jt + 1) * 16 + lr) * 64 + lq * 8);
      nxt[0] = p[0]; nxt[1] = p[1]; nxt[2] = p[8]; nxt[3] = p[9];
    }
    half8 b0 = cvt8(cur[0], cur[1]);
    half8 b1 = cvt8(cur[2], cur[3]);
    f32x4 acc = {0.f, 0.f, 0.f, 0.f};
    acc = __builtin_amdgcn_mfma_f32_16x16x32_f16(A0, b0, acc, 0, 0, 0);
    acc = __builtin_amdgcn_mfma_f32_16x16x32_f16(A1, b1, acc, 0, 0, 0);
    sa[jt] = acc;
    if (jt < 3) { cur[0] = nxt[0]; cur[1] = nxt[1]; cur[2] = nxt[2]; cur[3] = nxt[3]; }
  }

  // ---- prefetch u-phase B-frag it=0 (column dwords; L1/L2-hot second pass) ----
  float fT[16];
#pragma unroll
  for (int ks = 0; ks < 2; ++ks) {
    const float* gks = gbase + (ks * 32 + lq * 8) * 64 + lr;   // it=0: i = lr
#pragma unroll
    for (int e = 0; e < 8; ++e) fT[ks * 8 + e] = gks[e * 64];
  }

  // ---- softmax (valid in lq==0 lanes: s[h=reg][j=jt*16+lr]) ----
  float awv[4][4];   // [r][jt]
#pragma unroll
  for (int r = 0; r < 4; ++r) {
    float x[4];
#pragma unroll
    for (int jt = 0; jt < 4; ++jt)
      x[jt] = mreg[jt] ? sa[jt][r] * 0.125f : -INFINITY;
    float mx = fmaxf(fmaxf(x[0], x[1]), fmaxf(x[2], x[3]));
#pragma unroll
    for (int off = 8; off > 0; off >>= 1) mx = fmaxf(mx, __shfl_xor(mx, off));
    float p[4], sum = 0.f;
#pragma unroll
    for (int jt = 0; jt < 4; ++jt) {
      p[jt] = mreg[jt] ? __expf(x[jt] - mx) : 0.f;
      sum += p[jt];
    }
#pragma unroll
    for (int off = 8; off > 0; off >>= 1) sum += __shfl_xor(sum, off);
    float inv = (sum > 0.f) ? (1.f / sum) : 0.f;
#pragma unroll
    for (int jt = 0; jt < 4; ++jt) awv[r][jt] = p[jt] * inv;
  }
  if (lq == 0) {
#pragma unroll
    for (int r = 0; r < 4; ++r)
#pragma unroll
      for (int jt = 0; jt < 4; ++jt)
        qaw[r * 72 + jt * 16 + lr] = (_Float16)awv[r][jt];
  }

  LDS_FENCE();   // aw rows 0..3 visible before Au b128 reads (round-6 bug site)

  // ---- u-phase: A = aw (m=h, k=j), B = gg1^T columns (k=j, n=i) ----
  half8 Au0 = *reinterpret_cast<const half8*>(qaw + lr * 72 + lq * 8);
  half8 Au1 = *reinterpret_cast<const half8*>(qaw + lr * 72 + 32 + lq * 8);

  f32x4 ua[4];
#pragma unroll
  for (int it = 0; it < 4; ++it) {
    float fN[16];
    if (it < 3) {
#pragma unroll
      for (int ks = 0; ks < 2; ++ks) {
        const float* gks = gbase + (ks * 32 + lq * 8) * 64 + (it + 1) * 16 + lr;
#pragma unroll
        for (int e = 0; e < 8; ++e) fN[ks * 8 + e] = gks[e * 64];
      }
    }
    half8 b0, b1;
#pragma unroll
    for (int e = 0; e < 8; ++e) { b0[e] = (_Float16)fT[e]; b1[e] = (_Float16)fT[8 + e]; }
    f32x4 acc = {0.f, 0.f, 0.f, 0.f};
    acc = __builtin_amdgcn_mfma_f32_16x16x32_f16(Au0, b0, acc, 0, 0, 0);
    acc = __builtin_amdgcn_mfma_f32_16x16x32_f16(Au1, b1, acc, 0, 0, 0);
    ua[it] = acc;
    if (it < 3) {
#pragma unroll
      for (int e = 0; e < 16; ++e) fT[e] = fN[e];
    }
  }

  // publish u (lq==0 lanes hold u[h=reg][i=it*16+lr]) to flat us[h*64+i]
  if (lq == 0) {
#pragma unroll
    for (int r = 0; r < 4; ++r)
#pragma unroll
      for (int it = 0; it < 4; ++it)
        qaw[1216 + r * 64 + it * 16 + lr] = (_Float16)ua[it][r];
  }

  LDS_FENCE();   // us visible before the epilogue broadcast reads

  // ---- out[c=lane] = us . Wvh_t[c] + bh (256-term fp16 dot, fp32 acc) ----
  {
    const half8* usp  = reinterpret_cast<const half8*>(qaw + 1216);  // broadcast
    const half8* wrow = reinterpret_cast<const half8*>(Wvh + lane * 256);
    float o0 = 0.f, o1 = 0.f;
#pragma unroll
    for (int ks = 0; ks < 16; ++ks) {
      o0 = dot8(wrow[ks], usp[ks], o0);
      o1 = dot8(wrow[16 + ks], usp[16 + ks], o1);
    }
    out[(size_t)atom * 64 + lane] = o0 + o1 + bh[lane];
  }
}

}  // namespace

extern "C" void kernel_launch(void* const* d_in, const int* in_sizes, int n_in,
                              void* d_out, int out_size, void* d_ws, size_t ws_size,
                              hipStream_t stream) {
  const float* g1   = (const float*)d_in[0];
  const float* gg1  = (const float*)d_in[1];
  const int*   mask = (const int*)d_in[2];
  const float* Wq   = (const float*)d_in[3];
  const float* Wkv  = (const float*)d_in[4];
  const float* Wh   = (const float*)d_in[5];
  const float* bh   = (const float*)d_in[6];
  float* out = (float*)d_out;
  (void)in_sizes; (void)n_in; (void)ws_size; (void)out_size;

  _Float16* wpack = (_Float16*)d_ws;   // 32768 halfs = 64 KB
  pack_weights<<<128, 256, 0, stream>>>(Wq, Wkv, Wh, wpack);
  local_atten_kernel<<<NATOM / 4, 256, 0, stream>>>(g1, gg1, mask, wpack, bh, out);
}

// Round 10
// 234.313 us; speedup vs baseline: 1.1967x; 1.1612x over previous
//
#include <hip/hip_runtime.h>
#include <hip/hip_fp16.h>
#include <math.h>

#define NATOM 8192  // NB * NLOC

namespace {

typedef _Float16 half8 __attribute__((ext_vector_type(8)));
typedef _Float16 half2t __attribute__((ext_vector_type(2)));
typedef float f32x4 __attribute__((ext_vector_type(4)));

// Wave-internal LDS RAW fence: orders prior ds_writes against later ds_reads
// at both compiler level ("memory" clobber + sched_barrier) and HW level
// (lgkmcnt(0)). Does NOT touch vmcnt -> global prefetches stay in flight.
#define LDS_FENCE()                                        \
  do {                                                     \
    asm volatile("s_waitcnt lgkmcnt(0)" ::: "memory");     \
    __builtin_amdgcn_sched_barrier(0);                     \
  } while (0)

// ---- weight folding (33x FLOP cut) + MFMA B-fragment packing -------------
// ws layout (halfs): [0,16384) Mp | [16384,32768) Wp
//   M_flat[r=h*64+i][i'] = sum_d Wq[i'][d*4+h]   * Wkv[i][d*8+h]
//   Wvh   [c][k2=h*64+i] = sum_d Wkv[i][d*8+4+h] * Wh[(h*64+d)][c]
// Both stored in 16x16x32 B-frag order: for tile t, lane l, elem e the value
// is ROW (t%..*16 + (l&15)) at K (ks*32 + (l>>4)*8 + e) -> runtime loads are
// frag[t*64 + lane], fully coalesced 16B/lane (vs 64-line/instr per-lane rows).
__global__ void pack_weights(const float* __restrict__ Wq,
                             const float* __restrict__ Wkv,
                             const float* __restrict__ Wh,
                             _Float16* __restrict__ out) {
  int tid = blockIdx.x * 256 + threadIdx.x;   // 0..32767
  if (tid < 16384) {
    int r = tid >> 6, ip = tid & 63;          // r = h*64+i, ip = i'
    int h = r >> 6, i = r & 63;
    float acc = 0.f;
#pragma unroll 8
    for (int d = 0; d < 64; ++d)
      acc += Wq[ip * 256 + d * 4 + h] * Wkv[i * 512 + d * 8 + h];
    int mt = r >> 4, m = r & 15;
    int ks = ip >> 5, kk = ip & 31, lqk = kk >> 3, e = kk & 7;
    int l = lqk * 16 + m;
    out[(((mt * 2 + ks) * 64) + l) * 8 + e] = (_Float16)acc;
  } else {
    int idx = tid - 16384;
    int c = idx >> 8, k2 = idx & 255;         // k2 = h*64+i
    int h = k2 >> 6, i = k2 & 63;
    float acc = 0.f;
#pragma unroll 8
    for (int d = 0; d < 64; ++d)
      acc += Wkv[i * 512 + d * 8 + 4 + h] * Wh[(h * 64 + d) * 64 + c];
    int mt2 = c >> 4, m = c & 15;
    int ks2 = k2 >> 5, kk = k2 & 31, lqk = kk >> 3, e = kk & 7;
    int l = lqk * 16 + m;
    out[16384 + (((mt2 * 8 + ks2) * 64) + l) * 8 + e] = (_Float16)acc;
  }
}

__device__ __forceinline__ half8 cvt8(float4 a, float4 b) {
  half8 r;
  r[0] = (_Float16)a.x; r[1] = (_Float16)a.y; r[2] = (_Float16)a.z; r[3] = (_Float16)a.w;
  r[4] = (_Float16)b.x; r[5] = (_Float16)b.y; r[6] = (_Float16)b.z; r[7] = (_Float16)b.w;
  return r;
}

// ONE WAVE = ONE ATOM, zero barriers, 80 MFMAs/atom.
// qk~ and epilogue GEMVs use the broadcast-A identity: A rows all = x  =>
// D[m][n] = sum_k x[k]*B[k][n] for every m; D col n then holds output row
// tile*16+n in ALL lanes' rows (use reg 0, lq==0 lanes).
// LDS per wave (_Float16): rows 0..15 stride 72 (qk~/aw scratch), g1h @1152,
// us @1216. All four LDS RAW handoffs fenced (round-6 lesson).
__global__ __launch_bounds__(256, 4)
void local_atten_kernel(const float* __restrict__ g1,
                        const float* __restrict__ gg1,
                        const int* __restrict__ mask,
                        const _Float16* __restrict__ wpack,
                        const float* __restrict__ bh,
                        float* __restrict__ out) {
  __shared__ __align__(16) _Float16 qa[4][1536];   // 12288 B / block

  const _Float16* Mp = wpack;            // 16384 halfs, B-frag order
  const _Float16* Wp = wpack + 16384;    // 16384 halfs, B-frag order

  const int t = threadIdx.x;
  const int lane = t & 63;
  const int wave = t >> 6;
  const int lq = lane >> 4;
  const int lr = lane & 15;
  const int atom = blockIdx.x * 4 + wave;

  _Float16* qaw = qa[wave];
  const float* gbase = gg1 + (size_t)atom * 4096;

  // ---- early independent loads ----
  int mreg[4];
#pragma unroll
  for (int jt = 0; jt < 4; ++jt)
    mreg[jt] = mask[(size_t)atom * 64 + jt * 16 + lr];

  float bhv[4];
#pragma unroll
  for (int mt2 = 0; mt2 < 4; ++mt2) bhv[mt2] = bh[mt2 * 16 + lr];

  qaw[1152 + lane] = (_Float16)g1[(size_t)atom * 64 + lane];

  // zero unused A-scratch rows 4..15: s/u-phase MFMA A rows 4..15 read these
#pragma unroll
  for (int r = 4; r < 16; ++r) qaw[r * 72 + lane] = (_Float16)0.f;

  // first s-tile rows (jt=0) prefetch: row j=lr, i-chunks lq*8 and 32+lq*8
  float4 cur[4];
  {
    const float4* p = reinterpret_cast<const float4*>(gbase + lr * 64 + lq * 8);
    cur[0] = p[0]; cur[1] = p[1]; cur[2] = p[8]; cur[3] = p[9];   // +32 floats
  }

  LDS_FENCE();   // g1h (and zeros) visible

  // ---- qk~ = M_flat(256x64) @ g1 via MFMA, A = g1 broadcast ----
  // D col n (any row) = qk~[mt*16+n]; lq==0 lanes write 16 consecutive halfs.
  {
    const half8* mp = reinterpret_cast<const half8*>(Mp);
    half8 ag0 = *reinterpret_cast<const half8*>(qaw + 1152 + lq * 8);
    half8 ag1 = *reinterpret_cast<const half8*>(qaw + 1152 + 32 + lq * 8);
#pragma unroll 4
    for (int mt = 0; mt < 16; ++mt) {
      f32x4 acc = {0.f, 0.f, 0.f, 0.f};
      acc = __builtin_amdgcn_mfma_f32_16x16x32_f16(ag0, mp[(mt * 2) * 64 + lane], acc, 0, 0, 0);
      acc = __builtin_amdgcn_mfma_f32_16x16x32_f16(ag1, mp[(mt * 2 + 1) * 64 + lane], acc, 0, 0, 0);
      if (lq == 0)
        qaw[(mt >> 2) * 72 + (mt & 3) * 16 + lr] = (_Float16)acc[0];
    }
  }

  LDS_FENCE();   // qk~ rows 0..3 visible before A-frag b128 reads

  // ---- s-phase: A = qk~ (m=h, k=i), B = gg1 rows from global (k=i, n=j) ----
  half8 A0 = *reinterpret_cast<const half8*>(qaw + lr * 72 + lq * 8);
  half8 A1 = *reinterpret_cast<const half8*>(qaw + lr * 72 + 32 + lq * 8);

  f32x4 sa[4];
#pragma unroll
  for (int jt = 0; jt < 4; ++jt) {
    float4 nxt[4];
    if (jt < 3) {
      const float4* p =
          reinterpret_cast<const float4*>(gbase + ((jt + 1) * 16 + lr) * 64 + lq * 8);
      nxt[0] = p[0]; nxt[1] = p[1]; nxt[2] = p[8]; nxt[3] = p[9];
    }
    half8 b0 = cvt8(cur[0], cur[1]);
    half8 b1 = cvt8(cur[2], cur[3]);
    f32x4 acc = {0.f, 0.f, 0.f, 0.f};
    acc = __builtin_amdgcn_mfma_f32_16x16x32_f16(A0, b0, acc, 0, 0, 0);
    acc = __builtin_amdgcn_mfma_f32_16x16x32_f16(A1, b1, acc, 0, 0, 0);
    sa[jt] = acc;
    if (jt < 3) { cur[0] = nxt[0]; cur[1] = nxt[1]; cur[2] = nxt[2]; cur[3] = nxt[3]; }
  }

  // ---- prefetch u-phase B-frag it=0 (column dwords; L2/L3-hot second pass) ----
  float fT[16];
#pragma unroll
  for (int ks = 0; ks < 2; ++ks) {
    const float* gks = gbase + (ks * 32 + lq * 8) * 64 + lr;   // it=0: i = lr
#pragma unroll
    for (int e = 0; e < 8; ++e) fT[ks * 8 + e] = gks[e * 64];
  }

  // ---- softmax (valid in lq==0 lanes: s[h=reg][j=jt*16+lr]) ----
  float awv[4][4];   // [r][jt]
#pragma unroll
  for (int r = 0; r < 4; ++r) {
    float x[4];
#pragma unroll
    for (int jt = 0; jt < 4; ++jt)
      x[jt] = mreg[jt] ? sa[jt][r] * 0.125f : -INFINITY;
    float mx = fmaxf(fmaxf(x[0], x[1]), fmaxf(x[2], x[3]));
#pragma unroll
    for (int off = 8; off > 0; off >>= 1) mx = fmaxf(mx, __shfl_xor(mx, off));
    float p[4], sum = 0.f;
#pragma unroll
    for (int jt = 0; jt < 4; ++jt) {
      p[jt] = mreg[jt] ? __expf(x[jt] - mx) : 0.f;
      sum += p[jt];
    }
#pragma unroll
    for (int off = 8; off > 0; off >>= 1) sum += __shfl_xor(sum, off);
    float inv = (sum > 0.f) ? (1.f / sum) : 0.f;
#pragma unroll
    for (int jt = 0; jt < 4; ++jt) awv[r][jt] = p[jt] * inv;
  }
  if (lq == 0) {
#pragma unroll
    for (int r = 0; r < 4; ++r)
#pragma unroll
      for (int jt = 0; jt < 4; ++jt)
        qaw[r * 72 + jt * 16 + lr] = (_Float16)awv[r][jt];
  }

  LDS_FENCE();   // aw rows 0..3 visible before Au b128 reads

  // ---- u-phase: A = aw (m=h, k=j), B = gg1^T columns (k=j, n=i) ----
  half8 Au0 = *reinterpret_cast<const half8*>(qaw + lr * 72 + lq * 8);
  half8 Au1 = *reinterpret_cast<const half8*>(qaw + lr * 72 + 32 + lq * 8);

  f32x4 ua[4];
#pragma unroll
  for (int it = 0; it < 4; ++it) {
    float fN[16];
    if (it < 3) {
#pragma unroll
      for (int ks = 0; ks < 2; ++ks) {
        const float* gks = gbase + (ks * 32 + lq * 8) * 64 + (it + 1) * 16 + lr;
#pragma unroll
        for (int e = 0; e < 8; ++e) fN[ks * 8 + e] = gks[e * 64];
      }
    }
    half8 b0, b1;
#pragma unroll
    for (int e = 0; e < 8; ++e) { b0[e] = (_Float16)fT[e]; b1[e] = (_Float16)fT[8 + e]; }
    f32x4 acc = {0.f, 0.f, 0.f, 0.f};
    acc = __builtin_amdgcn_mfma_f32_16x16x32_f16(Au0, b0, acc, 0, 0, 0);
    acc = __builtin_amdgcn_mfma_f32_16x16x32_f16(Au1, b1, acc, 0, 0, 0);
    ua[it] = acc;
    if (it < 3) {
#pragma unroll
      for (int e = 0; e < 16; ++e) fT[e] = fN[e];
    }
  }

  // publish u (lq==0 lanes hold u[h=reg][i=it*16+lr]) to flat us[h*64+i]
  if (lq == 0) {
#pragma unroll
    for (int r = 0; r < 4; ++r)
#pragma unroll
      for (int it = 0; it < 4; ++it)
        qaw[1216 + r * 64 + it * 16 + lr] = (_Float16)ua[it][r];
  }

  LDS_FENCE();   // us visible before the epilogue A-broadcast reads

  // ---- out = Wvh(64x256) @ us via MFMA, A = us broadcast ----
  // D col n (any row) = out[mt2*16+n]; two parallel acc chains for ILP.
  {
    const half8* wp = reinterpret_cast<const half8*>(Wp);
    half8 au[8];
#pragma unroll
    for (int ks2 = 0; ks2 < 8; ++ks2)
      au[ks2] = *reinterpret_cast<const half8*>(qaw + 1216 + ks2 * 32 + lq * 8);
#pragma unroll 1
    for (int mt2 = 0; mt2 < 4; ++mt2) {
      f32x4 aa = {0.f, 0.f, 0.f, 0.f}, ab = {0.f, 0.f, 0.f, 0.f};
#pragma unroll
      for (int ks2 = 0; ks2 < 4; ++ks2) {
        aa = __builtin_amdgcn_mfma_f32_16x16x32_f16(au[ks2], wp[(mt2 * 8 + ks2) * 64 + lane], aa, 0, 0, 0);
        ab = __builtin_amdgcn_mfma_f32_16x16x32_f16(au[4 + ks2], wp[(mt2 * 8 + 4 + ks2) * 64 + lane], ab, 0, 0, 0);
      }
      if (lq == 0)
        out[(size_t)atom * 64 + mt2 * 16 + lr] = aa[0] + ab[0] + bhv[mt2];
    }
  }
}

}  // namespace

extern "C" void kernel_launch(void* const* d_in, const int* in_sizes, int n_in,
                              void* d_out, int out_size, void* d_ws, size_t ws_size,
                              hipStream_t stream) {
  const float* g1   = (const float*)d_in[0];
  const float* gg1  = (const float*)d_in[1];
  const int*   mask = (const int*)d_in[2];
  const float* Wq   = (const float*)d_in[3];
  const float* Wkv  = (const float*)d_in[4];
  const float* Wh   = (const float*)d_in[5];
  const float* bh   = (const float*)d_in[6];
  float* out = (float*)d_out;
  (void)in_sizes; (void)n_in; (void)ws_size; (void)out_size;

  _Float16* wpack = (_Float16*)d_ws;   // 32768 halfs = 64 KB
  pack_weights<<<128, 256, 0, stream>>>(Wq, Wkv, Wh, wpack);
  local_atten_kernel<<<NATOM / 4, 256, 0, stream>>>(g1, gg1, mask, wpack, bh, out);
}

// Round 11
// 233.922 us; speedup vs baseline: 1.1987x; 1.0017x over previous
//
#include <hip/hip_runtime.h>
#include <hip/hip_fp16.h>
#include <math.h>

#define NATOM 8192  // NB * NLOC

namespace {

typedef _Float16 half8 __attribute__((ext_vector_type(8)));
typedef _Float16 half2t __attribute__((ext_vector_type(2)));
typedef float f32x4 __attribute__((ext_vector_type(4)));

// Wave-internal LDS RAW fence: orders prior ds_writes against later ds_reads
// at both compiler level ("memory" clobber + sched_barrier) and HW level
// (lgkmcnt(0)). Does NOT touch vmcnt -> global prefetches stay in flight.
#define LDS_FENCE()                                        \
  do {                                                     \
    asm volatile("s_waitcnt lgkmcnt(0)" ::: "memory");     \
    __builtin_amdgcn_sched_barrier(0);                     \
  } while (0)

// ---- weight folding (33x FLOP cut) + MFMA B-fragment packing -------------
// ws layout (halfs): [0,16384) Mp | [16384,32768) Wp
//   M_flat[r=h*64+i][i'] = sum_d Wq[i'][d*4+h]   * Wkv[i][d*8+h]
//   Wvh   [c][k2=h*64+i] = sum_d Wkv[i][d*8+4+h] * Wh[(h*64+d)][c]
// Both stored in 16x16x32 B-frag order: for tile t, lane l, elem e the value
// is ROW (t%..*16 + (l&15)) at K (ks*32 + (l>>4)*8 + e) -> runtime loads are
// frag[t*64 + lane], fully coalesced 16B/lane (vs 64-line/instr per-lane rows).
__global__ void pack_weights(const float* __restrict__ Wq,
                             const float* __restrict__ Wkv,
                             const float* __restrict__ Wh,
                             _Float16* __restrict__ out) {
  int tid = blockIdx.x * 256 + threadIdx.x;   // 0..32767
  if (tid < 16384) {
    int r = tid >> 6, ip = tid & 63;          // r = h*64+i, ip = i'
    int h = r >> 6, i = r & 63;
    float acc = 0.f;
#pragma unroll 8
    for (int d = 0; d < 64; ++d)
      acc += Wq[ip * 256 + d * 4 + h] * Wkv[i * 512 + d * 8 + h];
    int mt = r >> 4, m = r & 15;
    int ks = ip >> 5, kk = ip & 31, lqk = kk >> 3, e = kk & 7;
    int l = lqk * 16 + m;
    out[(((mt * 2 + ks) * 64) + l) * 8 + e] = (_Float16)acc;
  } else {
    int idx = tid - 16384;
    int c = idx >> 8, k2 = idx & 255;         // k2 = h*64+i
    int h = k2 >> 6, i = k2 & 63;
    float acc = 0.f;
#pragma unroll 8
    for (int d = 0; d < 64; ++d)
      acc += Wkv[i * 512 + d * 8 + 4 + h] * Wh[(h * 64 + d) * 64 + c];
    int mt2 = c >> 4, m = c & 15;
    int ks2 = k2 >> 5, kk = k2 & 31, lqk = kk >> 3, e = kk & 7;
    int l = lqk * 16 + m;
    out[16384 + (((mt2 * 8 + ks2) * 64) + l) * 8 + e] = (_Float16)acc;
  }
}

__device__ __forceinline__ half8 cvt8(float4 a, float4 b) {
  half8 r;
  r[0] = (_Float16)a.x; r[1] = (_Float16)a.y; r[2] = (_Float16)a.z; r[3] = (_Float16)a.w;
  r[4] = (_Float16)b.x; r[5] = (_Float16)b.y; r[6] = (_Float16)b.z; r[7] = (_Float16)b.w;
  return r;
}

// ONE WAVE = ONE ATOM, zero barriers, 80 MFMAs/atom.
// DEEP PREFETCH (this round's change): all 16 s-row dwordx4 issued at wave
// start (HBM latency hides under the qk~ phase); all 64 u-column dwords
// issued right after the s-phase MFMAs (L2 latency hides under softmax +
// aw publish + fence). No load in the fenced critical path waits.
// qk~ and epilogue GEMVs use the broadcast-A identity: A rows all = x  =>
// D[m][n] = sum_k x[k]*B[k][n] for every m; D col n then holds output row
// tile*16+n in ALL lanes' rows (use reg 0, lq==0 lanes).
// LDS per wave (_Float16): rows 0..15 stride 72 (qk~/aw scratch), g1h @1152,
// us @1216. All four LDS RAW handoffs fenced (round-6 lesson).
__global__ __launch_bounds__(256, 4)
void local_atten_kernel(const float* __restrict__ g1,
                        const float* __restrict__ gg1,
                        const int* __restrict__ mask,
                        const _Float16* __restrict__ wpack,
                        const float* __restrict__ bh,
                        float* __restrict__ out) {
  __shared__ __align__(16) _Float16 qa[4][1536];   // 12288 B / block

  const _Float16* Mp = wpack;            // 16384 halfs, B-frag order
  const _Float16* Wp = wpack + 16384;    // 16384 halfs, B-frag order

  const int t = threadIdx.x;
  const int lane = t & 63;
  const int wave = t >> 6;
  const int lq = lane >> 4;
  const int lr = lane & 15;
  const int atom = blockIdx.x * 4 + wave;

  _Float16* qaw = qa[wave];
  const float* gbase = gg1 + (size_t)atom * 4096;

  // ---- early independent loads ----
  int mreg[4];
#pragma unroll
  for (int jt = 0; jt < 4; ++jt)
    mreg[jt] = mask[(size_t)atom * 64 + jt * 16 + lr];

  float bhv[4];
#pragma unroll
  for (int mt2 = 0; mt2 < 4; ++mt2) bhv[mt2] = bh[mt2 * 16 + lr];

  qaw[1152 + lane] = (_Float16)g1[(size_t)atom * 64 + lane];

  // ---- deep prefetch: ALL s-phase gg1 rows (16 dwordx4, 64 VGPRs) ----
  // row j = jt*16+lr, i-chunks lq*8 and 32+lq*8; consumed by s-phase MFMAs.
  float4 cur[4][4];
#pragma unroll
  for (int jt = 0; jt < 4; ++jt) {
    const float4* p =
        reinterpret_cast<const float4*>(gbase + (jt * 16 + lr) * 64 + lq * 8);
    cur[jt][0] = p[0]; cur[jt][1] = p[1]; cur[jt][2] = p[8]; cur[jt][3] = p[9];
  }

  // zero unused A-scratch rows 4..15: s/u-phase MFMA A rows 4..15 read these
#pragma unroll
  for (int r = 4; r < 16; ++r) qaw[r * 72 + lane] = (_Float16)0.f;

  LDS_FENCE();   // g1h (and zeros) visible

  // ---- qk~ = M_flat(256x64) @ g1 via MFMA, A = g1 broadcast ----
  // D col n (any row) = qk~[mt*16+n]; lq==0 lanes write 16 consecutive halfs.
  {
    const half8* mp = reinterpret_cast<const half8*>(Mp);
    half8 ag0 = *reinterpret_cast<const half8*>(qaw + 1152 + lq * 8);
    half8 ag1 = *reinterpret_cast<const half8*>(qaw + 1152 + 32 + lq * 8);
#pragma unroll 4
    for (int mt = 0; mt < 16; ++mt) {
      f32x4 acc = {0.f, 0.f, 0.f, 0.f};
      acc = __builtin_amdgcn_mfma_f32_16x16x32_f16(ag0, mp[(mt * 2) * 64 + lane], acc, 0, 0, 0);
      acc = __builtin_amdgcn_mfma_f32_16x16x32_f16(ag1, mp[(mt * 2 + 1) * 64 + lane], acc, 0, 0, 0);
      if (lq == 0)
        qaw[(mt >> 2) * 72 + (mt & 3) * 16 + lr] = (_Float16)acc[0];
    }
  }

  LDS_FENCE();   // qk~ rows 0..3 visible before A-frag b128 reads

  // ---- s-phase: A = qk~ (m=h, k=i), B = gg1 rows (prefetched; k=i, n=j) ----
  half8 A0 = *reinterpret_cast<const half8*>(qaw + lr * 72 + lq * 8);
  half8 A1 = *reinterpret_cast<const half8*>(qaw + lr * 72 + 32 + lq * 8);

  f32x4 sa[4];
#pragma unroll
  for (int jt = 0; jt < 4; ++jt) {
    half8 b0 = cvt8(cur[jt][0], cur[jt][1]);
    half8 b1 = cvt8(cur[jt][2], cur[jt][3]);
    f32x4 acc = {0.f, 0.f, 0.f, 0.f};
    acc = __builtin_amdgcn_mfma_f32_16x16x32_f16(A0, b0, acc, 0, 0, 0);
    acc = __builtin_amdgcn_mfma_f32_16x16x32_f16(A1, b1, acc, 0, 0, 0);
    sa[jt] = acc;
  }

  // ---- deep prefetch: ALL u-phase gg1 columns (64 dwords, 64 VGPRs) ----
  // j = ks*32+lq*8+e, i = it*16+lr; latency hides under softmax + fence.
  float fU[4][16];
#pragma unroll
  for (int it = 0; it < 4; ++it) {
#pragma unroll
    for (int ks = 0; ks < 2; ++ks) {
      const float* gks = gbase + (ks * 32 + lq * 8) * 64 + it * 16 + lr;
#pragma unroll
      for (int e = 0; e < 8; ++e) fU[it][ks * 8 + e] = gks[e * 64];
    }
  }

  // ---- softmax (valid in lq==0 lanes: s[h=reg][j=jt*16+lr]) ----
  float awv[4][4];   // [r][jt]
#pragma unroll
  for (int r = 0; r < 4; ++r) {
    float x[4];
#pragma unroll
    for (int jt = 0; jt < 4; ++jt)
      x[jt] = mreg[jt] ? sa[jt][r] * 0.125f : -INFINITY;
    float mx = fmaxf(fmaxf(x[0], x[1]), fmaxf(x[2], x[3]));
#pragma unroll
    for (int off = 8; off > 0; off >>= 1) mx = fmaxf(mx, __shfl_xor(mx, off));
    float p[4], sum = 0.f;
#pragma unroll
    for (int jt = 0; jt < 4; ++jt) {
      p[jt] = mreg[jt] ? __expf(x[jt] - mx) : 0.f;
      sum += p[jt];
    }
#pragma unroll
    for (int off = 8; off > 0; off >>= 1) sum += __shfl_xor(sum, off);
    float inv = (sum > 0.f) ? (1.f / sum) : 0.f;
#pragma unroll
    for (int jt = 0; jt < 4; ++jt) awv[r][jt] = p[jt] * inv;
  }
  if (lq == 0) {
#pragma unroll
    for (int r = 0; r < 4; ++r)
#pragma unroll
      for (int jt = 0; jt < 4; ++jt)
        qaw[r * 72 + jt * 16 + lr] = (_Float16)awv[r][jt];
  }

  LDS_FENCE();   // aw rows 0..3 visible before Au b128 reads

  // ---- u-phase: A = aw (m=h, k=j), B = gg1^T columns (prefetched) ----
  half8 Au0 = *reinterpret_cast<const half8*>(qaw + lr * 72 + lq * 8);
  half8 Au1 = *reinterpret_cast<const half8*>(qaw + lr * 72 + 32 + lq * 8);

  f32x4 ua[4];
#pragma unroll
  for (int it = 0; it < 4; ++it) {
    half8 b0, b1;
#pragma unroll
    for (int e = 0; e < 8; ++e) {
      b0[e] = (_Float16)fU[it][e];
      b1[e] = (_Float16)fU[it][8 + e];
    }
    f32x4 acc = {0.f, 0.f, 0.f, 0.f};
    acc = __builtin_amdgcn_mfma_f32_16x16x32_f16(Au0, b0, acc, 0, 0, 0);
    acc = __builtin_amdgcn_mfma_f32_16x16x32_f16(Au1, b1, acc, 0, 0, 0);
    ua[it] = acc;
  }

  // publish u (lq==0 lanes hold u[h=reg][i=it*16+lr]) to flat us[h*64+i]
  if (lq == 0) {
#pragma unroll
    for (int r = 0; r < 4; ++r)
#pragma unroll
      for (int it = 0; it < 4; ++it)
        qaw[1216 + r * 64 + it * 16 + lr] = (_Float16)ua[it][r];
  }

  LDS_FENCE();   // us visible before the epilogue A-broadcast reads

  // ---- out = Wvh(64x256) @ us via MFMA, A = us broadcast ----
  // D col n (any row) = out[mt2*16+n]; two parallel acc chains for ILP.
  {
    const half8* wp = reinterpret_cast<const half8*>(Wp);
    half8 au[8];
#pragma unroll
    for (int ks2 = 0; ks2 < 8; ++ks2)
      au[ks2] = *reinterpret_cast<const half8*>(qaw + 1216 + ks2 * 32 + lq * 8);
#pragma unroll 1
    for (int mt2 = 0; mt2 < 4; ++mt2) {
      f32x4 aa = {0.f, 0.f, 0.f, 0.f}, ab = {0.f, 0.f, 0.f, 0.f};
#pragma unroll
      for (int ks2 = 0; ks2 < 4; ++ks2) {
        aa = __builtin_amdgcn_mfma_f32_16x16x32_f16(au[ks2], wp[(mt2 * 8 + ks2) * 64 + lane], aa, 0, 0, 0);
        ab = __builtin_amdgcn_mfma_f32_16x16x32_f16(au[4 + ks2], wp[(mt2 * 8 + 4 + ks2) * 64 + lane], ab, 0, 0, 0);
      }
      if (lq == 0)
        out[(size_t)atom * 64 + mt2 * 16 + lr] = aa[0] + ab[0] + bhv[mt2];
    }
  }
}

}  // namespace

extern "C" void kernel_launch(void* const* d_in, const int* in_sizes, int n_in,
                              void* d_out, int out_size, void* d_ws, size_t ws_size,
                              hipStream_t stream) {
  const float* g1   = (const float*)d_in[0];
  const float* gg1  = (const float*)d_in[1];
  const int*   mask = (const int*)d_in[2];
  const float* Wq   = (const float*)d_in[3];
  const float* Wkv  = (const float*)d_in[4];
  const float* Wh   = (const float*)d_in[5];
  const float* bh   = (const float*)d_in[6];
  float* out = (float*)d_out;
  (void)in_sizes; (void)n_in; (void)ws_size; (void)out_size;

  _Float16* wpack = (_Float16*)d_ws;   // 32768 halfs = 64 KB
  pack_weights<<<128, 256, 0, stream>>>(Wq, Wkv, Wh, wpack);
  local_atten_kernel<<<NATOM / 4, 256, 0, stream>>>(g1, gg1, mask, wpack, bh, out);
}